// Round 8
// baseline (2221.426 us; speedup 1.0000x reference)
//
#include <hip/hip_runtime.h>
#include <hip/hip_fp16.h>
#include <cstdint>
#include <cstddef>

#define HW_NRAYS 16384
#define NSAMP    (1 << 21)
#define NLEV     12
#define TSZ      (1 << 19)
#define TMASK    (TSZ - 1)
#define DIN      24
#define HDIM     32
#define WS_TAB_QWORDS (NLEV * TSZ)
#define WS_TAB_BYTES  ((size_t)WS_TAB_QWORDS * 8)
#define WS_FEAT_BYTES ((size_t)NLEV * NSAMP * 8)
#define PRIME1 2654435761u
#define PRIME2 805459861u

__device__ __forceinline__ float clamp01f(float v) { return fminf(fmaxf(v, 0.f), 1.f); }

__device__ __forceinline__ uint32_t rne_bf16_lo(uint32_t u) {
    return (u + 0x7fffu + ((u >> 16) & 1u)) >> 16;
}
__device__ __forceinline__ float bf_lo(uint32_t v) { return __uint_as_float(v << 16); }
__device__ __forceinline__ float bf_hi(uint32_t v) { return __uint_as_float(v & 0xffff0000u); }

__global__ __launch_bounds__(256)
void ngp_pack_tables(const float2* __restrict__ tab_d,
                     const float2* __restrict__ tab_c,
                     uint2* __restrict__ ws_tab)
{
    const int stride = gridDim.x * blockDim.x;
    for (int i = blockIdx.x * blockDim.x + threadIdx.x; i < WS_TAB_QWORDS; i += stride) {
        const float2 d = tab_d[i];
        const float2 c = tab_c[i];
        const uint32_t w0 = rne_bf16_lo(__float_as_uint(d.x)) | (rne_bf16_lo(__float_as_uint(d.y)) << 16);
        const uint32_t w1 = rne_bf16_lo(__float_as_uint(c.x)) | (rne_bf16_lo(__float_as_uint(c.y)) << 16);
        ws_tab[i] = make_uint2(w0, w1);
    }
}

union H2U { __half2 h2; uint32_t u; };
union F4H2 { float4 f4; __half2 h2[4]; };

__device__ __forceinline__ void level_hashes(float x, float y, float z, int l,
                                             uint32_t* __restrict__ h,
                                             float* __restrict__ w)
{
    const float res1 = (float)((16 << l) - 1);
    const float px = x * res1, py = y * res1, pz = z * res1;
    const float fxf = floorf(px), fyf = floorf(py), fzf = floorf(pz);
    const uint32_t ix = (uint32_t)fxf, iy = (uint32_t)fyf, iz = (uint32_t)fzf;
    const float fx = px - fxf, fy = py - fyf, fz = pz - fzf;
    const uint32_t hx0 = ix, hx1 = ix + 1u;
    const uint32_t hy0 = iy * PRIME1, hy1 = hy0 + PRIME1;
    const uint32_t hz0 = iz * PRIME2, hz1 = hz0 + PRIME2;
    #pragma unroll
    for (int c = 0; c < 8; ++c) {
        h[c] = ((((c & 1) ? hx1 : hx0) ^ ((c & 2) ? hy1 : hy0) ^ ((c & 4) ? hz1 : hz0)) & TMASK);
        w[c] = ((c & 1) ? fx : 1.f - fx) * ((c & 2) ? fy : 1.f - fy) * ((c & 4) ? fz : 1.f - fz);
    }
}

// ---------------- encode: one thread = one (sample, level) ----------------
// Level-major grid: blocks of one level dispatch together, so each XCD's L2
// holds just that level's 4 MB table plane -> gathers are L2 hits instead of
// L3 traffic (round-7 lesson: FETCH, not occupancy, is the limiter).
__global__ __launch_bounds__(256)
void ngp_encode(const float* __restrict__ rays_o,
                const float* __restrict__ rays_d,
                const float* __restrict__ t_starts,
                const float* __restrict__ t_ends,
                const int*   __restrict__ ray_idx,
                const uint2* __restrict__ ws_tab,
                uint2* __restrict__ feat)
{
    const int l = blockIdx.x >> 13;                       // NSAMP/256 = 8192 blocks per level
    const int i = ((blockIdx.x & 8191) << 8) | threadIdx.x;

    const int ridx = ray_idx[i];
    const float tm = 0.5f * (t_starts[i] + t_ends[i]);
    const float x = clamp01f((rays_o[3 * ridx + 0] + rays_d[3 * ridx + 0] * tm + 1.f) * 0.5f);
    const float y = clamp01f((rays_o[3 * ridx + 1] + rays_d[3 * ridx + 1] * tm + 1.f) * 0.5f);
    const float z = clamp01f((rays_o[3 * ridx + 2] + rays_d[3 * ridx + 2] * tm + 1.f) * 0.5f);

    uint32_t h[8];
    float    w[8];
    level_hashes(x, y, z, l, h, w);

    const uint2* tl = ws_tab + (size_t)l * TSZ;
    uint2 v[8];
    #pragma unroll
    for (int c = 0; c < 8; ++c) v[c] = tl[h[c]];

    float a0 = 0.f, a1 = 0.f, b0 = 0.f, b1 = 0.f;
    #pragma unroll
    for (int c = 0; c < 8; ++c) {
        a0 += w[c] * bf_lo(v[c].x); a1 += w[c] * bf_hi(v[c].x);
        b0 += w[c] * bf_lo(v[c].y); b1 += w[c] * bf_hi(v[c].y);
    }
    H2U fD, fC;
    fD.h2 = __floats2half2_rn(a0, a1);
    fC.h2 = __floats2half2_rn(b0, b1);
    feat[(size_t)l * NSAMP + i] = make_uint2(fD.u, fC.u);
}

// ---------------- render from precomputed features ----------------
__global__ __launch_bounds__(256)
void ngp_render_feat(const float* __restrict__ t_starts,
                     const float* __restrict__ t_ends,
                     const int*   __restrict__ ray_idx,
                     const uint2* __restrict__ feat,
                     const float* __restrict__ w_d1,
                     const float* __restrict__ w_d2,
                     const float* __restrict__ w_c1,
                     const float* __restrict__ w_c2,
                     float* __restrict__ out)
{
    __shared__ __align__(16) __half2 s_wd1h[DIN * 16];
    __shared__ __align__(16) __half2 s_wc1h[DIN * 16];
    __shared__ __align__(16) float   s_wd2[HDIM];
    __shared__ __align__(16) float   s_wc2[HDIM * 3];

    const int tid = threadIdx.x;
    for (int idx = tid; idx < DIN * 16; idx += 256) {
        const int k = idx >> 4, j2 = idx & 15;
        s_wd1h[idx] = __floats2half2_rn(w_d1[k * HDIM + 2 * j2], w_d1[k * HDIM + 2 * j2 + 1]);
        s_wc1h[idx] = __floats2half2_rn(w_c1[k * HDIM + 2 * j2], w_c1[k * HDIM + 2 * j2 + 1]);
    }
    if (tid < HDIM) s_wd2[tid] = w_d2[tid];
    if (tid < HDIM * 3) s_wc2[tid] = w_c2[tid];
    __syncthreads();

    const int lane = tid & 63;
    const int r = blockIdx.x * 4 + (tid >> 6);

    int lo = 0, hi = NSAMP;
    while (lo < hi) { int m = (lo + hi) >> 1; if (ray_idx[m] < r) lo = m + 1; else hi = m; }
    const int start = lo;
    hi = NSAMP;
    while (lo < hi) { int m = (lo + hi) >> 1; if (ray_idx[m] <= r) lo = m + 1; else hi = m; }
    const int end = lo;

    float carry = 0.f, accw = 0.f, cr = 0.f, cg = 0.f, cb = 0.f;

    for (int base = start; base < end; base += 64) {
        const int i = base + lane;
        const bool valid = i < end;
        float sv = 0.f, R = 0.f, G = 0.f, B = 0.f;
        if (valid) {
            const float dt = t_ends[i] - t_starts[i];

            __half2 hbD2[16], hbC2[16];
            #pragma unroll
            for (int j = 0; j < 16; ++j) {
                hbD2[j] = __floats2half2_rn(0.f, 0.f);
                hbC2[j] = __floats2half2_rn(0.f, 0.f);
            }

            #pragma unroll
            for (int l = 0; l < NLEV; ++l) {
                const uint2 fv = feat[(size_t)l * NSAMP + i];
                H2U fD, fC; fD.u = fv.x; fC.u = fv.y;
                const __half2 a0h = __low2half2(fD.h2);
                const __half2 a1h = __high2half2(fD.h2);
                const __half2 b0h = __low2half2(fC.h2);
                const __half2 b1h = __high2half2(fC.h2);

                const F4H2* wd0 = (const F4H2*)(s_wd1h + (2 * l + 0) * 16);
                const F4H2* wd1 = (const F4H2*)(s_wd1h + (2 * l + 1) * 16);
                const F4H2* wc0 = (const F4H2*)(s_wc1h + (2 * l + 0) * 16);
                const F4H2* wc1 = (const F4H2*)(s_wc1h + (2 * l + 1) * 16);
                #pragma unroll
                for (int q = 0; q < 4; ++q) {
                    F4H2 u0 = wd0[q], u1 = wd1[q];
                    F4H2 v0 = wc0[q], v1 = wc1[q];
                    #pragma unroll
                    for (int p = 0; p < 4; ++p) {
                        hbD2[q * 4 + p] = __hfma2(a0h, u0.h2[p], __hfma2(a1h, u1.h2[p], hbD2[q * 4 + p]));
                        hbC2[q * 4 + p] = __hfma2(b0h, v0.h2[p], __hfma2(b1h, v1.h2[p], hbC2[q * 4 + p]));
                    }
                }
            }

            float sD = 0.f;
            #pragma unroll
            for (int j = 0; j < 16; ++j) {
                const float2 f = __half22float2(hbD2[j]);
                sD += fmaxf(f.x, 0.f) * s_wd2[2 * j] + fmaxf(f.y, 0.f) * s_wd2[2 * j + 1];
            }
            sv = __expf(sD) * dt;

            float pr = 0.f, pg = 0.f, pb = 0.f;
            #pragma unroll
            for (int j = 0; j < 16; ++j) {
                const float2 f = __half22float2(hbC2[j]);
                const float h0 = fmaxf(f.x, 0.f), h1 = fmaxf(f.y, 0.f);
                pr += h0 * s_wc2[3 * (2 * j) + 0] + h1 * s_wc2[3 * (2 * j + 1) + 0];
                pg += h0 * s_wc2[3 * (2 * j) + 1] + h1 * s_wc2[3 * (2 * j + 1) + 1];
                pb += h0 * s_wc2[3 * (2 * j) + 2] + h1 * s_wc2[3 * (2 * j + 1) + 2];
            }
            R = 1.f / (1.f + __expf(-pr));
            G = 1.f / (1.f + __expf(-pg));
            B = 1.f / (1.f + __expf(-pb));
        }

        float incl = sv;
        #pragma unroll
        for (int off = 1; off < 64; off <<= 1) {
            float t = __shfl_up(incl, off);
            if (lane >= off) incl += t;
        }
        const float e = carry + (incl - sv);
        const float w = valid ? (1.f - __expf(-sv)) * __expf(-e) : 0.f;
        accw += w; cr += w * R; cg += w * G; cb += w * B;
        carry += __shfl(incl, 63);
    }

    #pragma unroll
    for (int off = 32; off > 0; off >>= 1) {
        accw += __shfl_down(accw, off);
        cr   += __shfl_down(cr, off);
        cg   += __shfl_down(cg, off);
        cb   += __shfl_down(cb, off);
    }

    if (lane == 0) {
        const float bgw = 1.f - accw;   // BG_COLOR = 1.0
        out[0 * HW_NRAYS + r] = clamp01f(cr + bgw);
        out[1 * HW_NRAYS + r] = clamp01f(cg + bgw);
        out[2 * HW_NRAYS + r] = clamp01f(cb + bgw);
        out[3 * HW_NRAYS + r] = clamp01f(accw);
    }
}

// ---------------- round-6 fused kernel (fallback when ws fits only the table) ----------------
__global__ __launch_bounds__(256, 6)
void ngp_render_fast(const float* __restrict__ rays_o,
                     const float* __restrict__ rays_d,
                     const float* __restrict__ t_starts,
                     const float* __restrict__ t_ends,
                     const int*   __restrict__ ray_idx,
                     const uint2* __restrict__ ws_tab,
                     const float* __restrict__ w_d1,
                     const float* __restrict__ w_d2,
                     const float* __restrict__ w_c1,
                     const float* __restrict__ w_c2,
                     float* __restrict__ out)
{
    __shared__ __align__(16) __half2 s_wd1h[DIN * 16];
    __shared__ __align__(16) __half2 s_wc1h[DIN * 16];
    __shared__ __align__(16) float   s_wd2[HDIM];
    __shared__ __align__(16) float   s_wc2[HDIM * 3];
    __shared__ __align__(16) uint2   s_feat[4 * NLEV * 64];

    const int tid = threadIdx.x;
    for (int idx = tid; idx < DIN * 16; idx += 256) {
        const int k = idx >> 4, j2 = idx & 15;
        s_wd1h[idx] = __floats2half2_rn(w_d1[k * HDIM + 2 * j2], w_d1[k * HDIM + 2 * j2 + 1]);
        s_wc1h[idx] = __floats2half2_rn(w_c1[k * HDIM + 2 * j2], w_c1[k * HDIM + 2 * j2 + 1]);
    }
    if (tid < HDIM) s_wd2[tid] = w_d2[tid];
    if (tid < HDIM * 3) s_wc2[tid] = w_c2[tid];
    __syncthreads();

    const int lane = tid & 63;
    const int wv = tid >> 6;
    const int r = blockIdx.x * 4 + wv;
    uint2* const feat = s_feat + wv * (NLEV * 64) + lane;

    int lo = 0, hi = NSAMP;
    while (lo < hi) { int m = (lo + hi) >> 1; if (ray_idx[m] < r) lo = m + 1; else hi = m; }
    const int start = lo;
    hi = NSAMP;
    while (lo < hi) { int m = (lo + hi) >> 1; if (ray_idx[m] <= r) lo = m + 1; else hi = m; }
    const int end = lo;

    const float ox = rays_o[3 * r + 0], oy = rays_o[3 * r + 1], oz = rays_o[3 * r + 2];
    const float dx = rays_d[3 * r + 0], dy = rays_d[3 * r + 1], dz = rays_d[3 * r + 2];

    float carry = 0.f, accw = 0.f, cr = 0.f, cg = 0.f, cb = 0.f;

    for (int base = start; base < end; base += 64) {
        const int i = base + lane;
        const bool valid = i < end;
        float sv = 0.f, R = 0.f, G = 0.f, B = 0.f;
        if (valid) {
            const float ts = t_starts[i], te = t_ends[i];
            const float tm = 0.5f * (ts + te);
            const float x01x = clamp01f((ox + dx * tm + 1.f) * 0.5f);
            const float x01y = clamp01f((oy + dy * tm + 1.f) * 0.5f);
            const float x01z = clamp01f((oz + dz * tm + 1.f) * 0.5f);

            #pragma unroll 1
            for (int l = 0; l < NLEV; ++l) {
                uint32_t h[8]; float w[8];
                level_hashes(x01x, x01y, x01z, l, h, w);
                const uint2* tl = ws_tab + (size_t)l * TSZ;
                float a0 = 0.f, a1 = 0.f, b0 = 0.f, b1 = 0.f;
                #pragma unroll
                for (int c = 0; c < 8; ++c) {
                    const uint2 v = tl[h[c]];
                    a0 += w[c] * bf_lo(v.x); a1 += w[c] * bf_hi(v.x);
                    b0 += w[c] * bf_lo(v.y); b1 += w[c] * bf_hi(v.y);
                }
                H2U fD, fC;
                fD.h2 = __floats2half2_rn(a0, a1);
                fC.h2 = __floats2half2_rn(b0, b1);
                feat[l * 64] = make_uint2(fD.u, fC.u);
            }

            __half2 hbD2[16], hbC2[16];
            #pragma unroll
            for (int j = 0; j < 16; ++j) {
                hbD2[j] = __floats2half2_rn(0.f, 0.f);
                hbC2[j] = __floats2half2_rn(0.f, 0.f);
            }

            #pragma unroll
            for (int l = 0; l < NLEV; ++l) {
                const uint2 fv = feat[l * 64];
                H2U fD, fC; fD.u = fv.x; fC.u = fv.y;
                const __half2 a0h = __low2half2(fD.h2);
                const __half2 a1h = __high2half2(fD.h2);
                const __half2 b0h = __low2half2(fC.h2);
                const __half2 b1h = __high2half2(fC.h2);

                const F4H2* wd0 = (const F4H2*)(s_wd1h + (2 * l + 0) * 16);
                const F4H2* wd1 = (const F4H2*)(s_wd1h + (2 * l + 1) * 16);
                const F4H2* wc0 = (const F4H2*)(s_wc1h + (2 * l + 0) * 16);
                const F4H2* wc1 = (const F4H2*)(s_wc1h + (2 * l + 1) * 16);
                #pragma unroll
                for (int q = 0; q < 4; ++q) {
                    F4H2 u0 = wd0[q], u1 = wd1[q];
                    F4H2 v0 = wc0[q], v1 = wc1[q];
                    #pragma unroll
                    for (int p = 0; p < 4; ++p) {
                        hbD2[q * 4 + p] = __hfma2(a0h, u0.h2[p], __hfma2(a1h, u1.h2[p], hbD2[q * 4 + p]));
                        hbC2[q * 4 + p] = __hfma2(b0h, v0.h2[p], __hfma2(b1h, v1.h2[p], hbC2[q * 4 + p]));
                    }
                }
            }

            float sD = 0.f;
            #pragma unroll
            for (int j = 0; j < 16; ++j) {
                const float2 f = __half22float2(hbD2[j]);
                sD += fmaxf(f.x, 0.f) * s_wd2[2 * j] + fmaxf(f.y, 0.f) * s_wd2[2 * j + 1];
            }
            sv = __expf(sD) * (te - ts);

            float pr = 0.f, pg = 0.f, pb = 0.f;
            #pragma unroll
            for (int j = 0; j < 16; ++j) {
                const float2 f = __half22float2(hbC2[j]);
                const float h0 = fmaxf(f.x, 0.f), h1 = fmaxf(f.y, 0.f);
                pr += h0 * s_wc2[3 * (2 * j) + 0] + h1 * s_wc2[3 * (2 * j + 1) + 0];
                pg += h0 * s_wc2[3 * (2 * j) + 1] + h1 * s_wc2[3 * (2 * j + 1) + 1];
                pb += h0 * s_wc2[3 * (2 * j) + 2] + h1 * s_wc2[3 * (2 * j + 1) + 2];
            }
            R = 1.f / (1.f + __expf(-pr));
            G = 1.f / (1.f + __expf(-pg));
            B = 1.f / (1.f + __expf(-pb));
        }

        float incl = sv;
        #pragma unroll
        for (int off = 1; off < 64; off <<= 1) {
            float t = __shfl_up(incl, off);
            if (lane >= off) incl += t;
        }
        const float e = carry + (incl - sv);
        const float w = valid ? (1.f - __expf(-sv)) * __expf(-e) : 0.f;
        accw += w; cr += w * R; cg += w * G; cb += w * B;
        carry += __shfl(incl, 63);
    }

    #pragma unroll
    for (int off = 32; off > 0; off >>= 1) {
        accw += __shfl_down(accw, off);
        cr   += __shfl_down(cr, off);
        cg   += __shfl_down(cg, off);
        cb   += __shfl_down(cb, off);
    }

    if (lane == 0) {
        const float bgw = 1.f - accw;
        out[0 * HW_NRAYS + r] = clamp01f(cr + bgw);
        out[1 * HW_NRAYS + r] = clamp01f(cg + bgw);
        out[2 * HW_NRAYS + r] = clamp01f(cb + bgw);
        out[3 * HW_NRAYS + r] = clamp01f(accw);
    }
}

// ---------------- fallback (no workspace at all) ----------------
__global__ __launch_bounds__(64, 4)
void ngp_render_ref(const float* __restrict__ rays_o,
                    const float* __restrict__ rays_d,
                    const float* __restrict__ t_starts,
                    const float* __restrict__ t_ends,
                    const int*   __restrict__ ray_idx,
                    const float* __restrict__ tab_d,
                    const float* __restrict__ tab_c,
                    const float* __restrict__ w_d1,
                    const float* __restrict__ w_d2,
                    const float* __restrict__ w_c1,
                    const float* __restrict__ w_c2,
                    float* __restrict__ out)
{
    __shared__ __align__(16) float s_wd1[DIN * HDIM];
    __shared__ __align__(16) float s_wc1[DIN * HDIM];
    __shared__ __align__(16) float s_wd2[HDIM];
    __shared__ __align__(16) float s_wc2[HDIM * 3];

    const int lane = threadIdx.x;
    for (int i = lane; i < DIN * HDIM; i += 64) { s_wd1[i] = w_d1[i]; s_wc1[i] = w_c1[i]; }
    if (lane < HDIM) s_wd2[lane] = w_d2[lane];
    for (int i = lane; i < HDIM * 3; i += 64) s_wc2[i] = w_c2[i];
    __syncthreads();

    const int r = blockIdx.x;
    int lo = 0, hi = NSAMP;
    while (lo < hi) { int m = (lo + hi) >> 1; if (ray_idx[m] < r) lo = m + 1; else hi = m; }
    const int start = lo;
    hi = NSAMP;
    while (lo < hi) { int m = (lo + hi) >> 1; if (ray_idx[m] <= r) lo = m + 1; else hi = m; }
    const int end = lo;

    const float ox = rays_o[3 * r + 0], oy = rays_o[3 * r + 1], oz = rays_o[3 * r + 2];
    const float dx = rays_d[3 * r + 0], dy = rays_d[3 * r + 1], dz = rays_d[3 * r + 2];

    float carry = 0.f, accw = 0.f, cr = 0.f, cg = 0.f, cb = 0.f;

    for (int base = start; base < end; base += 64) {
        const int i = base + lane;
        const bool valid = i < end;
        float sv = 0.f, R = 0.f, G = 0.f, B = 0.f;
        if (valid) {
            const float ts = t_starts[i], te = t_ends[i];
            const float tm = 0.5f * (ts + te);
            const float x01x = clamp01f((ox + dx * tm + 1.f) * 0.5f);
            const float x01y = clamp01f((oy + dy * tm + 1.f) * 0.5f);
            const float x01z = clamp01f((oz + dz * tm + 1.f) * 0.5f);

            float hbD[HDIM], hbC[HDIM];
            #pragma unroll
            for (int j = 0; j < HDIM; ++j) { hbD[j] = 0.f; hbC[j] = 0.f; }

            #pragma unroll 1
            for (int l = 0; l < NLEV; ++l) {
                uint32_t h[8]; float w[8];
                level_hashes(x01x, x01y, x01z, l, h, w);
                const float* td = tab_d + (size_t)l * (TSZ * 2);
                const float* tc = tab_c + (size_t)l * (TSZ * 2);
                float a0 = 0.f, a1 = 0.f, b0 = 0.f, b1 = 0.f;
                #pragma unroll
                for (int c = 0; c < 8; ++c) {
                    const float2 vd = *(const float2*)(td + (size_t)(h[c] * 2u));
                    const float2 vc = *(const float2*)(tc + (size_t)(h[c] * 2u));
                    a0 += w[c] * vd.x; a1 += w[c] * vd.y; b0 += w[c] * vc.x; b1 += w[c] * vc.y;
                }
                #pragma unroll
                for (int j = 0; j < HDIM; j += 4) {
                    const float4 u0 = *(const float4*)(s_wd1 + (2 * l + 0) * HDIM + j);
                    const float4 u1 = *(const float4*)(s_wd1 + (2 * l + 1) * HDIM + j);
                    hbD[j + 0] += a0 * u0.x + a1 * u1.x;
                    hbD[j + 1] += a0 * u0.y + a1 * u1.y;
                    hbD[j + 2] += a0 * u0.z + a1 * u1.z;
                    hbD[j + 3] += a0 * u0.w + a1 * u1.w;
                    const float4 v0 = *(const float4*)(s_wc1 + (2 * l + 0) * HDIM + j);
                    const float4 v1 = *(const float4*)(s_wc1 + (2 * l + 1) * HDIM + j);
                    hbC[j + 0] += b0 * v0.x + b1 * v1.x;
                    hbC[j + 1] += b0 * v0.y + b1 * v1.y;
                    hbC[j + 2] += b0 * v0.z + b1 * v1.z;
                    hbC[j + 3] += b0 * v0.w + b1 * v1.w;
                }
            }

            float dotv = 0.f;
            #pragma unroll
            for (int j = 0; j < HDIM; ++j) dotv += fmaxf(hbD[j], 0.f) * s_wd2[j];
            sv = __expf(dotv) * (te - ts);

            float pr = 0.f, pg = 0.f, pb = 0.f;
            #pragma unroll
            for (int j = 0; j < HDIM; ++j) {
                const float hj = fmaxf(hbC[j], 0.f);
                pr += hj * s_wc2[3 * j + 0];
                pg += hj * s_wc2[3 * j + 1];
                pb += hj * s_wc2[3 * j + 2];
            }
            R = 1.f / (1.f + __expf(-pr));
            G = 1.f / (1.f + __expf(-pg));
            B = 1.f / (1.f + __expf(-pb));
        }

        float incl = sv;
        #pragma unroll
        for (int off = 1; off < 64; off <<= 1) {
            float t = __shfl_up(incl, off);
            if (lane >= off) incl += t;
        }
        const float e = carry + (incl - sv);
        const float w = valid ? (1.f - __expf(-sv)) * __expf(-e) : 0.f;
        accw += w; cr += w * R; cg += w * G; cb += w * B;
        carry += __shfl(incl, 63);
    }

    #pragma unroll
    for (int off = 32; off > 0; off >>= 1) {
        accw += __shfl_down(accw, off);
        cr   += __shfl_down(cr, off);
        cg   += __shfl_down(cg, off);
        cb   += __shfl_down(cb, off);
    }

    if (lane == 0) {
        const float bgw = 1.f - accw;
        out[0 * HW_NRAYS + r] = clamp01f(cr + bgw);
        out[1 * HW_NRAYS + r] = clamp01f(cg + bgw);
        out[2 * HW_NRAYS + r] = clamp01f(cb + bgw);
        out[3 * HW_NRAYS + r] = clamp01f(accw);
    }
}

extern "C" void kernel_launch(void* const* d_in, const int* in_sizes, int n_in,
                              void* d_out, int out_size, void* d_ws, size_t ws_size,
                              hipStream_t stream) {
    const float* rays_o        = (const float*)d_in[0];
    const float* rays_d        = (const float*)d_in[1];
    const float* t_starts      = (const float*)d_in[2];
    const float* t_ends        = (const float*)d_in[3];
    const int*   ray_indices   = (const int*)d_in[4];
    const float* table_density = (const float*)d_in[5];
    const float* table_color   = (const float*)d_in[6];
    const float* w_d1          = (const float*)d_in[7];
    const float* w_d2          = (const float*)d_in[8];
    const float* w_c1          = (const float*)d_in[9];
    const float* w_c2          = (const float*)d_in[10];
    float* outp = (float*)d_out;

    if (ws_size >= WS_TAB_BYTES + WS_FEAT_BYTES) {
        uint2* ws_tab = (uint2*)d_ws;
        uint2* ws_feat = (uint2*)((char*)d_ws + WS_TAB_BYTES);
        hipLaunchKernelGGL(ngp_pack_tables, dim3(4096), dim3(256), 0, stream,
                           (const float2*)table_density, (const float2*)table_color, ws_tab);
        hipLaunchKernelGGL(ngp_encode, dim3(NLEV * (NSAMP / 256)), dim3(256), 0, stream,
                           rays_o, rays_d, t_starts, t_ends, ray_indices, ws_tab, ws_feat);
        hipLaunchKernelGGL(ngp_render_feat, dim3(HW_NRAYS / 4), dim3(256), 0, stream,
                           t_starts, t_ends, ray_indices, ws_feat,
                           w_d1, w_d2, w_c1, w_c2, outp);
    } else if (ws_size >= WS_TAB_BYTES) {
        uint2* ws_tab = (uint2*)d_ws;
        hipLaunchKernelGGL(ngp_pack_tables, dim3(4096), dim3(256), 0, stream,
                           (const float2*)table_density, (const float2*)table_color, ws_tab);
        hipLaunchKernelGGL(ngp_render_fast, dim3(HW_NRAYS / 4), dim3(256), 0, stream,
                           rays_o, rays_d, t_starts, t_ends, ray_indices, ws_tab,
                           w_d1, w_d2, w_c1, w_c2, outp);
    } else {
        hipLaunchKernelGGL(ngp_render_ref, dim3(HW_NRAYS), dim3(64), 0, stream,
                           rays_o, rays_d, t_starts, t_ends, ray_indices,
                           table_density, table_color,
                           w_d1, w_d2, w_c1, w_c2, outp);
    }
}

// Round 9
// 862.041 us; speedup vs baseline: 2.5769x; 2.5769x over previous
//
#include <hip/hip_runtime.h>
#include <hip/hip_fp16.h>
#include <cstdint>
#include <cstddef>

#define HW_NRAYS 16384
#define NSAMP    (1 << 21)
#define NLEV     12
#define TSZ      (1 << 19)
#define TMASK    (TSZ - 1)
#define DIN      24
#define HDIM     32
#define WS_TAB_QWORDS (NLEV * TSZ)
#define WS_TAB_BYTES  ((size_t)WS_TAB_QWORDS * 8)
#define WS_FEAT_BYTES ((size_t)NLEV * NSAMP * 8)
#define PRIME1 2654435761u
#define PRIME2 805459861u

__device__ __forceinline__ float clamp01f(float v) { return fminf(fmaxf(v, 0.f), 1.f); }

__device__ __forceinline__ uint32_t rne_bf16_lo(uint32_t u) {
    return (u + 0x7fffu + ((u >> 16) & 1u)) >> 16;
}
__device__ __forceinline__ float bf_lo(uint32_t v) { return __uint_as_float(v << 16); }
__device__ __forceinline__ float bf_hi(uint32_t v) { return __uint_as_float(v & 0xffff0000u); }

__global__ __launch_bounds__(256)
void ngp_pack_tables(const float2* __restrict__ tab_d,
                     const float2* __restrict__ tab_c,
                     uint2* __restrict__ ws_tab)
{
    const int stride = gridDim.x * blockDim.x;
    for (int i = blockIdx.x * blockDim.x + threadIdx.x; i < WS_TAB_QWORDS; i += stride) {
        const float2 d = tab_d[i];
        const float2 c = tab_c[i];
        const uint32_t w0 = rne_bf16_lo(__float_as_uint(d.x)) | (rne_bf16_lo(__float_as_uint(d.y)) << 16);
        const uint32_t w1 = rne_bf16_lo(__float_as_uint(c.x)) | (rne_bf16_lo(__float_as_uint(c.y)) << 16);
        ws_tab[i] = make_uint2(w0, w1);
    }
}

union H2U { __half2 h2; uint32_t u; };
union F4H2 { float4 f4; __half2 h2[4]; };

__device__ __forceinline__ void level_hashes(float x, float y, float z, int l,
                                             uint32_t* __restrict__ h,
                                             float* __restrict__ w)
{
    const float res1 = (float)((16 << l) - 1);
    const float px = x * res1, py = y * res1, pz = z * res1;
    const float fxf = floorf(px), fyf = floorf(py), fzf = floorf(pz);
    const uint32_t ix = (uint32_t)fxf, iy = (uint32_t)fyf, iz = (uint32_t)fzf;
    const float fx = px - fxf, fy = py - fyf, fz = pz - fzf;
    const uint32_t hx0 = ix, hx1 = ix + 1u;
    const uint32_t hy0 = iy * PRIME1, hy1 = hy0 + PRIME1;
    const uint32_t hz0 = iz * PRIME2, hz1 = hz0 + PRIME2;
    #pragma unroll
    for (int c = 0; c < 8; ++c) {
        h[c] = ((((c & 1) ? hx1 : hx0) ^ ((c & 2) ? hy1 : hy0) ^ ((c & 4) ? hz1 : hz0)) & TMASK);
        w[c] = ((c & 1) ? fx : 1.f - fx) * ((c & 2) ? fy : 1.f - fy) * ((c & 4) ? fz : 1.f - fz);
    }
}

// ---------------- encode: one thread = one (sample, level) ----------------
// Level-major grid: blocks of one level dispatch together, so each XCD's L2
// holds mostly that level's 4 MB table plane -> gathers are L2 hits (round-8:
// verified, all gathers ~560 us total vs 1240 us fused).
__global__ __launch_bounds__(256)
void ngp_encode(const float* __restrict__ rays_o,
                const float* __restrict__ rays_d,
                const float* __restrict__ t_starts,
                const float* __restrict__ t_ends,
                const int*   __restrict__ ray_idx,
                const uint2* __restrict__ ws_tab,
                uint2* __restrict__ feat)
{
    const int l = blockIdx.x >> 13;                       // NSAMP/256 = 8192 blocks per level
    const int i = ((blockIdx.x & 8191) << 8) | threadIdx.x;

    const int ridx = ray_idx[i];
    const float tm = 0.5f * (t_starts[i] + t_ends[i]);
    const float x = clamp01f((rays_o[3 * ridx + 0] + rays_d[3 * ridx + 0] * tm + 1.f) * 0.5f);
    const float y = clamp01f((rays_o[3 * ridx + 1] + rays_d[3 * ridx + 1] * tm + 1.f) * 0.5f);
    const float z = clamp01f((rays_o[3 * ridx + 2] + rays_d[3 * ridx + 2] * tm + 1.f) * 0.5f);

    uint32_t h[8];
    float    w[8];
    level_hashes(x, y, z, l, h, w);

    const uint2* tl = ws_tab + (size_t)l * TSZ;
    uint2 v[8];
    #pragma unroll
    for (int c = 0; c < 8; ++c) v[c] = tl[h[c]];

    float a0 = 0.f, a1 = 0.f, b0 = 0.f, b1 = 0.f;
    #pragma unroll
    for (int c = 0; c < 8; ++c) {
        a0 += w[c] * bf_lo(v[c].x); a1 += w[c] * bf_hi(v[c].x);
        b0 += w[c] * bf_lo(v[c].y); b1 += w[c] * bf_hi(v[c].y);
    }
    H2U fD, fC;
    fD.h2 = __floats2half2_rn(a0, a1);
    fC.h2 = __floats2half2_rn(b0, b1);
    feat[(size_t)l * NSAMP + i] = make_uint2(fD.u, fC.u);
}

// Process one level's packed features into both fp16 hidden accumulators.
// All accumulator indexing is static (macro + full unrolls) -> stays in VGPRs.
#define PROC_LEVEL(FV, LIDX)                                                     \
    do {                                                                         \
        H2U fDu, fCu; fDu.u = (FV).x; fCu.u = (FV).y;                            \
        const __half2 a0h = __low2half2(fDu.h2), a1h = __high2half2(fDu.h2);     \
        const __half2 b0h = __low2half2(fCu.h2), b1h = __high2half2(fCu.h2);     \
        const F4H2* wd0 = (const F4H2*)(s_wd1h + (2 * (LIDX) + 0) * 16);         \
        const F4H2* wd1 = (const F4H2*)(s_wd1h + (2 * (LIDX) + 1) * 16);         \
        const F4H2* wc0 = (const F4H2*)(s_wc1h + (2 * (LIDX) + 0) * 16);         \
        const F4H2* wc1 = (const F4H2*)(s_wc1h + (2 * (LIDX) + 1) * 16);         \
        _Pragma("unroll")                                                        \
        for (int q = 0; q < 4; ++q) {                                            \
            F4H2 u0 = wd0[q], u1 = wd1[q], v0 = wc0[q], v1 = wc1[q];             \
            _Pragma("unroll")                                                    \
            for (int p = 0; p < 4; ++p) {                                        \
                hbD2[q * 4 + p] = __hfma2(a0h, u0.h2[p],                         \
                                    __hfma2(a1h, u1.h2[p], hbD2[q * 4 + p]));    \
                hbC2[q * 4 + p] = __hfma2(b0h, v0.h2[p],                         \
                                    __hfma2(b1h, v1.h2[p], hbC2[q * 4 + p]));    \
            }                                                                    \
        }                                                                        \
    } while (0)

// ---------------- render from precomputed features ----------------
// unroll(1) over 2 groups of 6 levels: 6 coalesced loads in flight, then
// consume; keeps the scheduling window small (round-8 lesson: full 12-level
// unroll with global loads -> 256 VGPR + 1.9 GB spill).
__global__ __launch_bounds__(256)
void ngp_render_feat(const float* __restrict__ t_starts,
                     const float* __restrict__ t_ends,
                     const int*   __restrict__ ray_idx,
                     const uint2* __restrict__ feat,
                     const float* __restrict__ w_d1,
                     const float* __restrict__ w_d2,
                     const float* __restrict__ w_c1,
                     const float* __restrict__ w_c2,
                     float* __restrict__ out)
{
    __shared__ __align__(16) __half2 s_wd1h[DIN * 16];
    __shared__ __align__(16) __half2 s_wc1h[DIN * 16];
    __shared__ __align__(16) float   s_wd2[HDIM];
    __shared__ __align__(16) float   s_wc2[HDIM * 3];

    const int tid = threadIdx.x;
    for (int idx = tid; idx < DIN * 16; idx += 256) {
        const int k = idx >> 4, j2 = idx & 15;
        s_wd1h[idx] = __floats2half2_rn(w_d1[k * HDIM + 2 * j2], w_d1[k * HDIM + 2 * j2 + 1]);
        s_wc1h[idx] = __floats2half2_rn(w_c1[k * HDIM + 2 * j2], w_c1[k * HDIM + 2 * j2 + 1]);
    }
    if (tid < HDIM) s_wd2[tid] = w_d2[tid];
    if (tid < HDIM * 3) s_wc2[tid] = w_c2[tid];
    __syncthreads();

    const int lane = tid & 63;
    const int r = blockIdx.x * 4 + (tid >> 6);

    int lo = 0, hi = NSAMP;
    while (lo < hi) { int m = (lo + hi) >> 1; if (ray_idx[m] < r) lo = m + 1; else hi = m; }
    const int start = lo;
    hi = NSAMP;
    while (lo < hi) { int m = (lo + hi) >> 1; if (ray_idx[m] <= r) lo = m + 1; else hi = m; }
    const int end = lo;

    float carry = 0.f, accw = 0.f, cr = 0.f, cg = 0.f, cb = 0.f;

    for (int base = start; base < end; base += 64) {
        const int i = base + lane;
        const bool valid = i < end;
        float sv = 0.f, R = 0.f, G = 0.f, B = 0.f;
        if (valid) {
            const float dt = t_ends[i] - t_starts[i];

            __half2 hbD2[16], hbC2[16];
            #pragma unroll
            for (int j = 0; j < 16; ++j) {
                hbD2[j] = __floats2half2_rn(0.f, 0.f);
                hbC2[j] = __floats2half2_rn(0.f, 0.f);
            }

            const uint2* fpl = feat + i;
            #pragma unroll 1
            for (int lg = 0; lg < NLEV; lg += 6) {
                const uint2 f0 = fpl[(size_t)(lg + 0) * NSAMP];
                const uint2 f1 = fpl[(size_t)(lg + 1) * NSAMP];
                const uint2 f2 = fpl[(size_t)(lg + 2) * NSAMP];
                const uint2 f3 = fpl[(size_t)(lg + 3) * NSAMP];
                const uint2 f4 = fpl[(size_t)(lg + 4) * NSAMP];
                const uint2 f5 = fpl[(size_t)(lg + 5) * NSAMP];
                PROC_LEVEL(f0, lg + 0);
                PROC_LEVEL(f1, lg + 1);
                PROC_LEVEL(f2, lg + 2);
                PROC_LEVEL(f3, lg + 3);
                PROC_LEVEL(f4, lg + 4);
                PROC_LEVEL(f5, lg + 5);
            }

            float sD = 0.f;
            #pragma unroll
            for (int j = 0; j < 16; ++j) {
                const float2 f = __half22float2(hbD2[j]);
                sD += fmaxf(f.x, 0.f) * s_wd2[2 * j] + fmaxf(f.y, 0.f) * s_wd2[2 * j + 1];
            }
            sv = __expf(sD) * dt;

            float pr = 0.f, pg = 0.f, pb = 0.f;
            #pragma unroll
            for (int j = 0; j < 16; ++j) {
                const float2 f = __half22float2(hbC2[j]);
                const float h0 = fmaxf(f.x, 0.f), h1 = fmaxf(f.y, 0.f);
                pr += h0 * s_wc2[3 * (2 * j) + 0] + h1 * s_wc2[3 * (2 * j + 1) + 0];
                pg += h0 * s_wc2[3 * (2 * j) + 1] + h1 * s_wc2[3 * (2 * j + 1) + 1];
                pb += h0 * s_wc2[3 * (2 * j) + 2] + h1 * s_wc2[3 * (2 * j + 1) + 2];
            }
            R = 1.f / (1.f + __expf(-pr));
            G = 1.f / (1.f + __expf(-pg));
            B = 1.f / (1.f + __expf(-pb));
        }

        float incl = sv;
        #pragma unroll
        for (int off = 1; off < 64; off <<= 1) {
            float t = __shfl_up(incl, off);
            if (lane >= off) incl += t;
        }
        const float e = carry + (incl - sv);
        const float w = valid ? (1.f - __expf(-sv)) * __expf(-e) : 0.f;
        accw += w; cr += w * R; cg += w * G; cb += w * B;
        carry += __shfl(incl, 63);
    }

    #pragma unroll
    for (int off = 32; off > 0; off >>= 1) {
        accw += __shfl_down(accw, off);
        cr   += __shfl_down(cr, off);
        cg   += __shfl_down(cg, off);
        cb   += __shfl_down(cb, off);
    }

    if (lane == 0) {
        const float bgw = 1.f - accw;   // BG_COLOR = 1.0
        out[0 * HW_NRAYS + r] = clamp01f(cr + bgw);
        out[1 * HW_NRAYS + r] = clamp01f(cg + bgw);
        out[2 * HW_NRAYS + r] = clamp01f(cb + bgw);
        out[3 * HW_NRAYS + r] = clamp01f(accw);
    }
}

// ---------------- round-6 fused kernel (fallback when ws fits only the table) ----------------
__global__ __launch_bounds__(256, 6)
void ngp_render_fast(const float* __restrict__ rays_o,
                     const float* __restrict__ rays_d,
                     const float* __restrict__ t_starts,
                     const float* __restrict__ t_ends,
                     const int*   __restrict__ ray_idx,
                     const uint2* __restrict__ ws_tab,
                     const float* __restrict__ w_d1,
                     const float* __restrict__ w_d2,
                     const float* __restrict__ w_c1,
                     const float* __restrict__ w_c2,
                     float* __restrict__ out)
{
    __shared__ __align__(16) __half2 s_wd1h[DIN * 16];
    __shared__ __align__(16) __half2 s_wc1h[DIN * 16];
    __shared__ __align__(16) float   s_wd2[HDIM];
    __shared__ __align__(16) float   s_wc2[HDIM * 3];
    __shared__ __align__(16) uint2   s_feat[4 * NLEV * 64];

    const int tid = threadIdx.x;
    for (int idx = tid; idx < DIN * 16; idx += 256) {
        const int k = idx >> 4, j2 = idx & 15;
        s_wd1h[idx] = __floats2half2_rn(w_d1[k * HDIM + 2 * j2], w_d1[k * HDIM + 2 * j2 + 1]);
        s_wc1h[idx] = __floats2half2_rn(w_c1[k * HDIM + 2 * j2], w_c1[k * HDIM + 2 * j2 + 1]);
    }
    if (tid < HDIM) s_wd2[tid] = w_d2[tid];
    if (tid < HDIM * 3) s_wc2[tid] = w_c2[tid];
    __syncthreads();

    const int lane = tid & 63;
    const int wv = tid >> 6;
    const int r = blockIdx.x * 4 + wv;
    uint2* const feat = s_feat + wv * (NLEV * 64) + lane;

    int lo = 0, hi = NSAMP;
    while (lo < hi) { int m = (lo + hi) >> 1; if (ray_idx[m] < r) lo = m + 1; else hi = m; }
    const int start = lo;
    hi = NSAMP;
    while (lo < hi) { int m = (lo + hi) >> 1; if (ray_idx[m] <= r) lo = m + 1; else hi = m; }
    const int end = lo;

    const float ox = rays_o[3 * r + 0], oy = rays_o[3 * r + 1], oz = rays_o[3 * r + 2];
    const float dx = rays_d[3 * r + 0], dy = rays_d[3 * r + 1], dz = rays_d[3 * r + 2];

    float carry = 0.f, accw = 0.f, cr = 0.f, cg = 0.f, cb = 0.f;

    for (int base = start; base < end; base += 64) {
        const int i = base + lane;
        const bool valid = i < end;
        float sv = 0.f, R = 0.f, G = 0.f, B = 0.f;
        if (valid) {
            const float ts = t_starts[i], te = t_ends[i];
            const float tm = 0.5f * (ts + te);
            const float x01x = clamp01f((ox + dx * tm + 1.f) * 0.5f);
            const float x01y = clamp01f((oy + dy * tm + 1.f) * 0.5f);
            const float x01z = clamp01f((oz + dz * tm + 1.f) * 0.5f);

            #pragma unroll 1
            for (int l = 0; l < NLEV; ++l) {
                uint32_t h[8]; float w[8];
                level_hashes(x01x, x01y, x01z, l, h, w);
                const uint2* tl = ws_tab + (size_t)l * TSZ;
                float a0 = 0.f, a1 = 0.f, b0 = 0.f, b1 = 0.f;
                #pragma unroll
                for (int c = 0; c < 8; ++c) {
                    const uint2 v = tl[h[c]];
                    a0 += w[c] * bf_lo(v.x); a1 += w[c] * bf_hi(v.x);
                    b0 += w[c] * bf_lo(v.y); b1 += w[c] * bf_hi(v.y);
                }
                H2U fD, fC;
                fD.h2 = __floats2half2_rn(a0, a1);
                fC.h2 = __floats2half2_rn(b0, b1);
                feat[l * 64] = make_uint2(fD.u, fC.u);
            }

            __half2 hbD2[16], hbC2[16];
            #pragma unroll
            for (int j = 0; j < 16; ++j) {
                hbD2[j] = __floats2half2_rn(0.f, 0.f);
                hbC2[j] = __floats2half2_rn(0.f, 0.f);
            }

            #pragma unroll
            for (int l = 0; l < NLEV; ++l) {
                const uint2 fv = feat[l * 64];
                PROC_LEVEL(fv, l);
            }

            float sD = 0.f;
            #pragma unroll
            for (int j = 0; j < 16; ++j) {
                const float2 f = __half22float2(hbD2[j]);
                sD += fmaxf(f.x, 0.f) * s_wd2[2 * j] + fmaxf(f.y, 0.f) * s_wd2[2 * j + 1];
            }
            sv = __expf(sD) * (te - ts);

            float pr = 0.f, pg = 0.f, pb = 0.f;
            #pragma unroll
            for (int j = 0; j < 16; ++j) {
                const float2 f = __half22float2(hbC2[j]);
                const float h0 = fmaxf(f.x, 0.f), h1 = fmaxf(f.y, 0.f);
                pr += h0 * s_wc2[3 * (2 * j) + 0] + h1 * s_wc2[3 * (2 * j + 1) + 0];
                pg += h0 * s_wc2[3 * (2 * j) + 1] + h1 * s_wc2[3 * (2 * j + 1) + 1];
                pb += h0 * s_wc2[3 * (2 * j) + 2] + h1 * s_wc2[3 * (2 * j + 1) + 2];
            }
            R = 1.f / (1.f + __expf(-pr));
            G = 1.f / (1.f + __expf(-pg));
            B = 1.f / (1.f + __expf(-pb));
        }

        float incl = sv;
        #pragma unroll
        for (int off = 1; off < 64; off <<= 1) {
            float t = __shfl_up(incl, off);
            if (lane >= off) incl += t;
        }
        const float e = carry + (incl - sv);
        const float w = valid ? (1.f - __expf(-sv)) * __expf(-e) : 0.f;
        accw += w; cr += w * R; cg += w * G; cb += w * B;
        carry += __shfl(incl, 63);
    }

    #pragma unroll
    for (int off = 32; off > 0; off >>= 1) {
        accw += __shfl_down(accw, off);
        cr   += __shfl_down(cr, off);
        cg   += __shfl_down(cg, off);
        cb   += __shfl_down(cb, off);
    }

    if (lane == 0) {
        const float bgw = 1.f - accw;
        out[0 * HW_NRAYS + r] = clamp01f(cr + bgw);
        out[1 * HW_NRAYS + r] = clamp01f(cg + bgw);
        out[2 * HW_NRAYS + r] = clamp01f(cb + bgw);
        out[3 * HW_NRAYS + r] = clamp01f(accw);
    }
}

// ---------------- fallback (no workspace at all) ----------------
__global__ __launch_bounds__(64, 4)
void ngp_render_ref(const float* __restrict__ rays_o,
                    const float* __restrict__ rays_d,
                    const float* __restrict__ t_starts,
                    const float* __restrict__ t_ends,
                    const int*   __restrict__ ray_idx,
                    const float* __restrict__ tab_d,
                    const float* __restrict__ tab_c,
                    const float* __restrict__ w_d1,
                    const float* __restrict__ w_d2,
                    const float* __restrict__ w_c1,
                    const float* __restrict__ w_c2,
                    float* __restrict__ out)
{
    __shared__ __align__(16) float s_wd1[DIN * HDIM];
    __shared__ __align__(16) float s_wc1[DIN * HDIM];
    __shared__ __align__(16) float s_wd2[HDIM];
    __shared__ __align__(16) float s_wc2[HDIM * 3];

    const int lane = threadIdx.x;
    for (int i = lane; i < DIN * HDIM; i += 64) { s_wd1[i] = w_d1[i]; s_wc1[i] = w_c1[i]; }
    if (lane < HDIM) s_wd2[lane] = w_d2[lane];
    for (int i = lane; i < HDIM * 3; i += 64) s_wc2[i] = w_c2[i];
    __syncthreads();

    const int r = blockIdx.x;
    int lo = 0, hi = NSAMP;
    while (lo < hi) { int m = (lo + hi) >> 1; if (ray_idx[m] < r) lo = m + 1; else hi = m; }
    const int start = lo;
    hi = NSAMP;
    while (lo < hi) { int m = (lo + hi) >> 1; if (ray_idx[m] <= r) lo = m + 1; else hi = m; }
    const int end = lo;

    const float ox = rays_o[3 * r + 0], oy = rays_o[3 * r + 1], oz = rays_o[3 * r + 2];
    const float dx = rays_d[3 * r + 0], dy = rays_d[3 * r + 1], dz = rays_d[3 * r + 2];

    float carry = 0.f, accw = 0.f, cr = 0.f, cg = 0.f, cb = 0.f;

    for (int base = start; base < end; base += 64) {
        const int i = base + lane;
        const bool valid = i < end;
        float sv = 0.f, R = 0.f, G = 0.f, B = 0.f;
        if (valid) {
            const float ts = t_starts[i], te = t_ends[i];
            const float tm = 0.5f * (ts + te);
            const float x01x = clamp01f((ox + dx * tm + 1.f) * 0.5f);
            const float x01y = clamp01f((oy + dy * tm + 1.f) * 0.5f);
            const float x01z = clamp01f((oz + dz * tm + 1.f) * 0.5f);

            float hbD[HDIM], hbC[HDIM];
            #pragma unroll
            for (int j = 0; j < HDIM; ++j) { hbD[j] = 0.f; hbC[j] = 0.f; }

            #pragma unroll 1
            for (int l = 0; l < NLEV; ++l) {
                uint32_t h[8]; float w[8];
                level_hashes(x01x, x01y, x01z, l, h, w);
                const float* td = tab_d + (size_t)l * (TSZ * 2);
                const float* tc = tab_c + (size_t)l * (TSZ * 2);
                float a0 = 0.f, a1 = 0.f, b0 = 0.f, b1 = 0.f;
                #pragma unroll
                for (int c = 0; c < 8; ++c) {
                    const float2 vd = *(const float2*)(td + (size_t)(h[c] * 2u));
                    const float2 vc = *(const float2*)(tc + (size_t)(h[c] * 2u));
                    a0 += w[c] * vd.x; a1 += w[c] * vd.y; b0 += w[c] * vc.x; b1 += w[c] * vc.y;
                }
                #pragma unroll
                for (int j = 0; j < HDIM; j += 4) {
                    const float4 u0 = *(const float4*)(s_wd1 + (2 * l + 0) * HDIM + j);
                    const float4 u1 = *(const float4*)(s_wd1 + (2 * l + 1) * HDIM + j);
                    hbD[j + 0] += a0 * u0.x + a1 * u1.x;
                    hbD[j + 1] += a0 * u0.y + a1 * u1.y;
                    hbD[j + 2] += a0 * u0.z + a1 * u1.z;
                    hbD[j + 3] += a0 * u0.w + a1 * u1.w;
                    const float4 v0 = *(const float4*)(s_wc1 + (2 * l + 0) * HDIM + j);
                    const float4 v1 = *(const float4*)(s_wc1 + (2 * l + 1) * HDIM + j);
                    hbC[j + 0] += b0 * v0.x + b1 * v1.x;
                    hbC[j + 1] += b0 * v0.y + b1 * v1.y;
                    hbC[j + 2] += b0 * v0.z + b1 * v1.z;
                    hbC[j + 3] += b0 * v0.w + b1 * v1.w;
                }
            }

            float dotv = 0.f;
            #pragma unroll
            for (int j = 0; j < HDIM; ++j) dotv += fmaxf(hbD[j], 0.f) * s_wd2[j];
            sv = __expf(dotv) * (te - ts);

            float pr = 0.f, pg = 0.f, pb = 0.f;
            #pragma unroll
            for (int j = 0; j < HDIM; ++j) {
                const float hj = fmaxf(hbC[j], 0.f);
                pr += hj * s_wc2[3 * j + 0];
                pg += hj * s_wc2[3 * j + 1];
                pb += hj * s_wc2[3 * j + 2];
            }
            R = 1.f / (1.f + __expf(-pr));
            G = 1.f / (1.f + __expf(-pg));
            B = 1.f / (1.f + __expf(-pb));
        }

        float incl = sv;
        #pragma unroll
        for (int off = 1; off < 64; off <<= 1) {
            float t = __shfl_up(incl, off);
            if (lane >= off) incl += t;
        }
        const float e = carry + (incl - sv);
        const float w = valid ? (1.f - __expf(-sv)) * __expf(-e) : 0.f;
        accw += w; cr += w * R; cg += w * G; cb += w * B;
        carry += __shfl(incl, 63);
    }

    #pragma unroll
    for (int off = 32; off > 0; off >>= 1) {
        accw += __shfl_down(accw, off);
        cr   += __shfl_down(cr, off);
        cg   += __shfl_down(cg, off);
        cb   += __shfl_down(cb, off);
    }

    if (lane == 0) {
        const float bgw = 1.f - accw;
        out[0 * HW_NRAYS + r] = clamp01f(cr + bgw);
        out[1 * HW_NRAYS + r] = clamp01f(cg + bgw);
        out[2 * HW_NRAYS + r] = clamp01f(cb + bgw);
        out[3 * HW_NRAYS + r] = clamp01f(accw);
    }
}

extern "C" void kernel_launch(void* const* d_in, const int* in_sizes, int n_in,
                              void* d_out, int out_size, void* d_ws, size_t ws_size,
                              hipStream_t stream) {
    const float* rays_o        = (const float*)d_in[0];
    const float* rays_d        = (const float*)d_in[1];
    const float* t_starts      = (const float*)d_in[2];
    const float* t_ends        = (const float*)d_in[3];
    const int*   ray_indices   = (const int*)d_in[4];
    const float* table_density = (const float*)d_in[5];
    const float* table_color   = (const float*)d_in[6];
    const float* w_d1          = (const float*)d_in[7];
    const float* w_d2          = (const float*)d_in[8];
    const float* w_c1          = (const float*)d_in[9];
    const float* w_c2          = (const float*)d_in[10];
    float* outp = (float*)d_out;

    if (ws_size >= WS_TAB_BYTES + WS_FEAT_BYTES) {
        uint2* ws_tab = (uint2*)d_ws;
        uint2* ws_feat = (uint2*)((char*)d_ws + WS_TAB_BYTES);
        hipLaunchKernelGGL(ngp_pack_tables, dim3(4096), dim3(256), 0, stream,
                           (const float2*)table_density, (const float2*)table_color, ws_tab);
        hipLaunchKernelGGL(ngp_encode, dim3(NLEV * (NSAMP / 256)), dim3(256), 0, stream,
                           rays_o, rays_d, t_starts, t_ends, ray_indices, ws_tab, ws_feat);
        hipLaunchKernelGGL(ngp_render_feat, dim3(HW_NRAYS / 4), dim3(256), 0, stream,
                           t_starts, t_ends, ray_indices, ws_feat,
                           w_d1, w_d2, w_c1, w_c2, outp);
    } else if (ws_size >= WS_TAB_BYTES) {
        uint2* ws_tab = (uint2*)d_ws;
        hipLaunchKernelGGL(ngp_pack_tables, dim3(4096), dim3(256), 0, stream,
                           (const float2*)table_density, (const float2*)table_color, ws_tab);
        hipLaunchKernelGGL(ngp_render_fast, dim3(HW_NRAYS / 4), dim3(256), 0, stream,
                           rays_o, rays_d, t_starts, t_ends, ray_indices, ws_tab,
                           w_d1, w_d2, w_c1, w_c2, outp);
    } else {
        hipLaunchKernelGGL(ngp_render_ref, dim3(HW_NRAYS), dim3(64), 0, stream,
                           rays_o, rays_d, t_starts, t_ends, ray_indices,
                           table_density, table_color,
                           w_d1, w_d2, w_c1, w_c2, outp);
    }
}

// Round 10
// 803.663 us; speedup vs baseline: 2.7641x; 1.0726x over previous
//
#include <hip/hip_runtime.h>
#include <hip/hip_fp16.h>
#include <cstdint>
#include <cstddef>

#define HW_NRAYS 16384
#define NSAMP    (1 << 21)
#define NLEV     12
#define TSZ      (1 << 19)
#define TMASK    (TSZ - 1)
#define DIN      24
#define HDIM     32
#define WS_TAB_QWORDS (NLEV * TSZ)
#define WS_TAB_BYTES  ((size_t)WS_TAB_QWORDS * 8)
#define WS_FEAT_BYTES ((size_t)NLEV * NSAMP * 8)
#define PRIME1 2654435761u
#define PRIME2 805459861u

__device__ __forceinline__ float clamp01f(float v) { return fminf(fmaxf(v, 0.f), 1.f); }

__device__ __forceinline__ uint32_t rne_bf16_lo(uint32_t u) {
    return (u + 0x7fffu + ((u >> 16) & 1u)) >> 16;
}
__device__ __forceinline__ float bf_lo(uint32_t v) { return __uint_as_float(v << 16); }
__device__ __forceinline__ float bf_hi(uint32_t v) { return __uint_as_float(v & 0xffff0000u); }

__global__ __launch_bounds__(256)
void ngp_pack_tables(const float2* __restrict__ tab_d,
                     const float2* __restrict__ tab_c,
                     uint2* __restrict__ ws_tab)
{
    const int stride = gridDim.x * blockDim.x;
    for (int i = blockIdx.x * blockDim.x + threadIdx.x; i < WS_TAB_QWORDS; i += stride) {
        const float2 d = tab_d[i];
        const float2 c = tab_c[i];
        const uint32_t w0 = rne_bf16_lo(__float_as_uint(d.x)) | (rne_bf16_lo(__float_as_uint(d.y)) << 16);
        const uint32_t w1 = rne_bf16_lo(__float_as_uint(c.x)) | (rne_bf16_lo(__float_as_uint(c.y)) << 16);
        ws_tab[i] = make_uint2(w0, w1);
    }
}

union H2U { __half2 h2; uint32_t u; };
union F4H2 { float4 f4; __half2 h2[4]; };

__device__ __forceinline__ void level_hashes(float x, float y, float z, int l,
                                             uint32_t* __restrict__ h,
                                             float* __restrict__ w)
{
    const float res1 = (float)((16 << l) - 1);
    const float px = x * res1, py = y * res1, pz = z * res1;
    const float fxf = floorf(px), fyf = floorf(py), fzf = floorf(pz);
    const uint32_t ix = (uint32_t)fxf, iy = (uint32_t)fyf, iz = (uint32_t)fzf;
    const float fx = px - fxf, fy = py - fyf, fz = pz - fzf;
    const uint32_t hx0 = ix, hx1 = ix + 1u;
    const uint32_t hy0 = iy * PRIME1, hy1 = hy0 + PRIME1;
    const uint32_t hz0 = iz * PRIME2, hz1 = hz0 + PRIME2;
    #pragma unroll
    for (int c = 0; c < 8; ++c) {
        h[c] = ((((c & 1) ? hx1 : hx0) ^ ((c & 2) ? hy1 : hy0) ^ ((c & 4) ? hz1 : hz0)) & TMASK);
        w[c] = ((c & 1) ? fx : 1.f - fx) * ((c & 2) ? fy : 1.f - fy) * ((c & 4) ? fz : 1.f - fz);
    }
}

// ---------------- encode: one thread = one (sample, level) ----------------
// Level-major grid keeps one 4 MB table plane L2-resident per XCD (round-8/9:
// verified). Round-10: (a) 16B pair-gathers -- PRIMES[0]==1 makes x-corner
// pairs (h, h^1) share a 16B-aligned pair when ix is even; second pair-load is
// predicated per-lane so ~25% fewer TA requests. (b) non-temporal feature
// stores so the 201 MB write stream doesn't evict the table plane from L2.
__global__ __launch_bounds__(256)
void ngp_encode(const float* __restrict__ rays_o,
                const float* __restrict__ rays_d,
                const float* __restrict__ t_starts,
                const float* __restrict__ t_ends,
                const int*   __restrict__ ray_idx,
                const uint2* __restrict__ ws_tab,
                uint2* __restrict__ feat)
{
    const int l = blockIdx.x >> 13;                       // NSAMP/256 = 8192 blocks per level
    const int i = ((blockIdx.x & 8191) << 8) | threadIdx.x;

    const int ridx = ray_idx[i];
    const float tm = 0.5f * (t_starts[i] + t_ends[i]);
    const float x = clamp01f((rays_o[3 * ridx + 0] + rays_d[3 * ridx + 0] * tm + 1.f) * 0.5f);
    const float y = clamp01f((rays_o[3 * ridx + 1] + rays_d[3 * ridx + 1] * tm + 1.f) * 0.5f);
    const float z = clamp01f((rays_o[3 * ridx + 2] + rays_d[3 * ridx + 2] * tm + 1.f) * 0.5f);

    const float res1 = (float)((16 << l) - 1);
    const float px = x * res1, py = y * res1, pz = z * res1;
    const float fxf = floorf(px), fyf = floorf(py), fzf = floorf(pz);
    const uint32_t ix = (uint32_t)fxf, iy = (uint32_t)fyf, iz = (uint32_t)fzf;
    const float fx = px - fxf, fy = py - fyf, fz = pz - fzf;
    const float wx0 = 1.f - fx, wx1 = fx;

    const uint32_t hy0 = iy * PRIME1, hy1 = hy0 + PRIME1;
    const uint32_t hz0 = iz * PRIME2, hz1 = hz0 + PRIME2;

    uint32_t hyz[4];
    float    wyz[4];
    hyz[0] = hy0 ^ hz0; wyz[0] = (1.f - fy) * (1.f - fz);
    hyz[1] = hy1 ^ hz0; wyz[1] = fy * (1.f - fz);
    hyz[2] = hy0 ^ hz1; wyz[2] = (1.f - fy) * fz;
    hyz[3] = hy1 ^ hz1; wyz[3] = fy * fz;

    const uint4* pairs = (const uint4*)(ws_tab + (size_t)l * TSZ);

    float a0 = 0.f, a1 = 0.f, b0 = 0.f, b1 = 0.f;
    #pragma unroll
    for (int k = 0; k < 4; ++k) {
        const uint32_t h0 = (ix        ^ hyz[k]) & TMASK;
        const uint32_t h1 = ((ix + 1u) ^ hyz[k]) & TMASK;
        uint4 q0 = pairs[h0 >> 1];
        uint4 q1 = q0;
        if ((h1 >> 1) != (h0 >> 1)) q1 = pairs[h1 >> 1];   // predicated: no request when shared
        const uint32_t e0x = (h0 & 1u) ? q0.z : q0.x;
        const uint32_t e0y = (h0 & 1u) ? q0.w : q0.y;
        const uint32_t e1x = (h1 & 1u) ? q1.z : q1.x;
        const uint32_t e1y = (h1 & 1u) ? q1.w : q1.y;
        const float w0 = wx0 * wyz[k], w1 = wx1 * wyz[k];
        a0 += w0 * bf_lo(e0x) + w1 * bf_lo(e1x);
        a1 += w0 * bf_hi(e0x) + w1 * bf_hi(e1x);
        b0 += w0 * bf_lo(e0y) + w1 * bf_lo(e1y);
        b1 += w0 * bf_hi(e0y) + w1 * bf_hi(e1y);
    }

    H2U fD, fC;
    fD.h2 = __floats2half2_rn(a0, a1);
    fC.h2 = __floats2half2_rn(b0, b1);
    const unsigned long long packed = (unsigned long long)fD.u | ((unsigned long long)fC.u << 32);
    __builtin_nontemporal_store(packed, (unsigned long long*)(feat + (size_t)l * NSAMP + i));
}

// Process one level's packed features into both fp16 hidden accumulators.
// All accumulator indexing is static (macro + full unrolls) -> stays in VGPRs.
#define PROC_LEVEL(FV, LIDX)                                                     \
    do {                                                                         \
        H2U fDu, fCu; fDu.u = (FV).x; fCu.u = (FV).y;                            \
        const __half2 a0h = __low2half2(fDu.h2), a1h = __high2half2(fDu.h2);     \
        const __half2 b0h = __low2half2(fCu.h2), b1h = __high2half2(fCu.h2);     \
        const F4H2* wd0 = (const F4H2*)(s_wd1h + (2 * (LIDX) + 0) * 16);         \
        const F4H2* wd1 = (const F4H2*)(s_wd1h + (2 * (LIDX) + 1) * 16);         \
        const F4H2* wc0 = (const F4H2*)(s_wc1h + (2 * (LIDX) + 0) * 16);         \
        const F4H2* wc1 = (const F4H2*)(s_wc1h + (2 * (LIDX) + 1) * 16);         \
        _Pragma("unroll")                                                        \
        for (int q = 0; q < 4; ++q) {                                            \
            F4H2 u0 = wd0[q], u1 = wd1[q], v0 = wc0[q], v1 = wc1[q];             \
            _Pragma("unroll")                                                    \
            for (int p = 0; p < 4; ++p) {                                        \
                hbD2[q * 4 + p] = __hfma2(a0h, u0.h2[p],                         \
                                    __hfma2(a1h, u1.h2[p], hbD2[q * 4 + p]));    \
                hbC2[q * 4 + p] = __hfma2(b0h, v0.h2[p],                         \
                                    __hfma2(b1h, v1.h2[p], hbC2[q * 4 + p]));    \
            }                                                                    \
        }                                                                        \
    } while (0)

// ---------------- render from precomputed features ----------------
// unroll(1) over 2 groups of 6 levels: 6 coalesced loads in flight, then
// consume; keeps the scheduling window small (round-8 lesson: full 12-level
// unroll with global loads -> 256 VGPR + 1.9 GB spill).
__global__ __launch_bounds__(256)
void ngp_render_feat(const float* __restrict__ t_starts,
                     const float* __restrict__ t_ends,
                     const int*   __restrict__ ray_idx,
                     const uint2* __restrict__ feat,
                     const float* __restrict__ w_d1,
                     const float* __restrict__ w_d2,
                     const float* __restrict__ w_c1,
                     const float* __restrict__ w_c2,
                     float* __restrict__ out)
{
    __shared__ __align__(16) __half2 s_wd1h[DIN * 16];
    __shared__ __align__(16) __half2 s_wc1h[DIN * 16];
    __shared__ __align__(16) float   s_wd2[HDIM];
    __shared__ __align__(16) float   s_wc2[HDIM * 3];

    const int tid = threadIdx.x;
    for (int idx = tid; idx < DIN * 16; idx += 256) {
        const int k = idx >> 4, j2 = idx & 15;
        s_wd1h[idx] = __floats2half2_rn(w_d1[k * HDIM + 2 * j2], w_d1[k * HDIM + 2 * j2 + 1]);
        s_wc1h[idx] = __floats2half2_rn(w_c1[k * HDIM + 2 * j2], w_c1[k * HDIM + 2 * j2 + 1]);
    }
    if (tid < HDIM) s_wd2[tid] = w_d2[tid];
    if (tid < HDIM * 3) s_wc2[tid] = w_c2[tid];
    __syncthreads();

    const int lane = tid & 63;
    const int r = blockIdx.x * 4 + (tid >> 6);

    int lo = 0, hi = NSAMP;
    while (lo < hi) { int m = (lo + hi) >> 1; if (ray_idx[m] < r) lo = m + 1; else hi = m; }
    const int start = lo;
    hi = NSAMP;
    while (lo < hi) { int m = (lo + hi) >> 1; if (ray_idx[m] <= r) lo = m + 1; else hi = m; }
    const int end = lo;

    float carry = 0.f, accw = 0.f, cr = 0.f, cg = 0.f, cb = 0.f;

    for (int base = start; base < end; base += 64) {
        const int i = base + lane;
        const bool valid = i < end;
        float sv = 0.f, R = 0.f, G = 0.f, B = 0.f;
        if (valid) {
            const float dt = t_ends[i] - t_starts[i];

            __half2 hbD2[16], hbC2[16];
            #pragma unroll
            for (int j = 0; j < 16; ++j) {
                hbD2[j] = __floats2half2_rn(0.f, 0.f);
                hbC2[j] = __floats2half2_rn(0.f, 0.f);
            }

            const uint2* fpl = feat + i;
            #pragma unroll 1
            for (int lg = 0; lg < NLEV; lg += 6) {
                const uint2 f0 = fpl[(size_t)(lg + 0) * NSAMP];
                const uint2 f1 = fpl[(size_t)(lg + 1) * NSAMP];
                const uint2 f2 = fpl[(size_t)(lg + 2) * NSAMP];
                const uint2 f3 = fpl[(size_t)(lg + 3) * NSAMP];
                const uint2 f4 = fpl[(size_t)(lg + 4) * NSAMP];
                const uint2 f5 = fpl[(size_t)(lg + 5) * NSAMP];
                PROC_LEVEL(f0, lg + 0);
                PROC_LEVEL(f1, lg + 1);
                PROC_LEVEL(f2, lg + 2);
                PROC_LEVEL(f3, lg + 3);
                PROC_LEVEL(f4, lg + 4);
                PROC_LEVEL(f5, lg + 5);
            }

            float sD = 0.f;
            #pragma unroll
            for (int j = 0; j < 16; ++j) {
                const float2 f = __half22float2(hbD2[j]);
                sD += fmaxf(f.x, 0.f) * s_wd2[2 * j] + fmaxf(f.y, 0.f) * s_wd2[2 * j + 1];
            }
            sv = __expf(sD) * dt;

            float pr = 0.f, pg = 0.f, pb = 0.f;
            #pragma unroll
            for (int j = 0; j < 16; ++j) {
                const float2 f = __half22float2(hbC2[j]);
                const float h0 = fmaxf(f.x, 0.f), h1 = fmaxf(f.y, 0.f);
                pr += h0 * s_wc2[3 * (2 * j) + 0] + h1 * s_wc2[3 * (2 * j + 1) + 0];
                pg += h0 * s_wc2[3 * (2 * j) + 1] + h1 * s_wc2[3 * (2 * j + 1) + 1];
                pb += h0 * s_wc2[3 * (2 * j) + 2] + h1 * s_wc2[3 * (2 * j + 1) + 2];
            }
            R = 1.f / (1.f + __expf(-pr));
            G = 1.f / (1.f + __expf(-pg));
            B = 1.f / (1.f + __expf(-pb));
        }

        float incl = sv;
        #pragma unroll
        for (int off = 1; off < 64; off <<= 1) {
            float t = __shfl_up(incl, off);
            if (lane >= off) incl += t;
        }
        const float e = carry + (incl - sv);
        const float w = valid ? (1.f - __expf(-sv)) * __expf(-e) : 0.f;
        accw += w; cr += w * R; cg += w * G; cb += w * B;
        carry += __shfl(incl, 63);
    }

    #pragma unroll
    for (int off = 32; off > 0; off >>= 1) {
        accw += __shfl_down(accw, off);
        cr   += __shfl_down(cr, off);
        cg   += __shfl_down(cg, off);
        cb   += __shfl_down(cb, off);
    }

    if (lane == 0) {
        const float bgw = 1.f - accw;   // BG_COLOR = 1.0
        out[0 * HW_NRAYS + r] = clamp01f(cr + bgw);
        out[1 * HW_NRAYS + r] = clamp01f(cg + bgw);
        out[2 * HW_NRAYS + r] = clamp01f(cb + bgw);
        out[3 * HW_NRAYS + r] = clamp01f(accw);
    }
}

// ---------------- round-6 fused kernel (fallback when ws fits only the table) ----------------
__global__ __launch_bounds__(256, 6)
void ngp_render_fast(const float* __restrict__ rays_o,
                     const float* __restrict__ rays_d,
                     const float* __restrict__ t_starts,
                     const float* __restrict__ t_ends,
                     const int*   __restrict__ ray_idx,
                     const uint2* __restrict__ ws_tab,
                     const float* __restrict__ w_d1,
                     const float* __restrict__ w_d2,
                     const float* __restrict__ w_c1,
                     const float* __restrict__ w_c2,
                     float* __restrict__ out)
{
    __shared__ __align__(16) __half2 s_wd1h[DIN * 16];
    __shared__ __align__(16) __half2 s_wc1h[DIN * 16];
    __shared__ __align__(16) float   s_wd2[HDIM];
    __shared__ __align__(16) float   s_wc2[HDIM * 3];
    __shared__ __align__(16) uint2   s_feat[4 * NLEV * 64];

    const int tid = threadIdx.x;
    for (int idx = tid; idx < DIN * 16; idx += 256) {
        const int k = idx >> 4, j2 = idx & 15;
        s_wd1h[idx] = __floats2half2_rn(w_d1[k * HDIM + 2 * j2], w_d1[k * HDIM + 2 * j2 + 1]);
        s_wc1h[idx] = __floats2half2_rn(w_c1[k * HDIM + 2 * j2], w_c1[k * HDIM + 2 * j2 + 1]);
    }
    if (tid < HDIM) s_wd2[tid] = w_d2[tid];
    if (tid < HDIM * 3) s_wc2[tid] = w_c2[tid];
    __syncthreads();

    const int lane = tid & 63;
    const int wv = tid >> 6;
    const int r = blockIdx.x * 4 + wv;
    uint2* const feat = s_feat + wv * (NLEV * 64) + lane;

    int lo = 0, hi = NSAMP;
    while (lo < hi) { int m = (lo + hi) >> 1; if (ray_idx[m] < r) lo = m + 1; else hi = m; }
    const int start = lo;
    hi = NSAMP;
    while (lo < hi) { int m = (lo + hi) >> 1; if (ray_idx[m] <= r) lo = m + 1; else hi = m; }
    const int end = lo;

    const float ox = rays_o[3 * r + 0], oy = rays_o[3 * r + 1], oz = rays_o[3 * r + 2];
    const float dx = rays_d[3 * r + 0], dy = rays_d[3 * r + 1], dz = rays_d[3 * r + 2];

    float carry = 0.f, accw = 0.f, cr = 0.f, cg = 0.f, cb = 0.f;

    for (int base = start; base < end; base += 64) {
        const int i = base + lane;
        const bool valid = i < end;
        float sv = 0.f, R = 0.f, G = 0.f, B = 0.f;
        if (valid) {
            const float ts = t_starts[i], te = t_ends[i];
            const float tm = 0.5f * (ts + te);
            const float x01x = clamp01f((ox + dx * tm + 1.f) * 0.5f);
            const float x01y = clamp01f((oy + dy * tm + 1.f) * 0.5f);
            const float x01z = clamp01f((oz + dz * tm + 1.f) * 0.5f);

            #pragma unroll 1
            for (int l = 0; l < NLEV; ++l) {
                uint32_t h[8]; float w[8];
                level_hashes(x01x, x01y, x01z, l, h, w);
                const uint2* tl = ws_tab + (size_t)l * TSZ;
                float a0 = 0.f, a1 = 0.f, b0 = 0.f, b1 = 0.f;
                #pragma unroll
                for (int c = 0; c < 8; ++c) {
                    const uint2 v = tl[h[c]];
                    a0 += w[c] * bf_lo(v.x); a1 += w[c] * bf_hi(v.x);
                    b0 += w[c] * bf_lo(v.y); b1 += w[c] * bf_hi(v.y);
                }
                H2U fD, fC;
                fD.h2 = __floats2half2_rn(a0, a1);
                fC.h2 = __floats2half2_rn(b0, b1);
                feat[l * 64] = make_uint2(fD.u, fC.u);
            }

            __half2 hbD2[16], hbC2[16];
            #pragma unroll
            for (int j = 0; j < 16; ++j) {
                hbD2[j] = __floats2half2_rn(0.f, 0.f);
                hbC2[j] = __floats2half2_rn(0.f, 0.f);
            }

            #pragma unroll
            for (int l = 0; l < NLEV; ++l) {
                const uint2 fv = feat[l * 64];
                PROC_LEVEL(fv, l);
            }

            float sD = 0.f;
            #pragma unroll
            for (int j = 0; j < 16; ++j) {
                const float2 f = __half22float2(hbD2[j]);
                sD += fmaxf(f.x, 0.f) * s_wd2[2 * j] + fmaxf(f.y, 0.f) * s_wd2[2 * j + 1];
            }
            sv = __expf(sD) * (te - ts);

            float pr = 0.f, pg = 0.f, pb = 0.f;
            #pragma unroll
            for (int j = 0; j < 16; ++j) {
                const float2 f = __half22float2(hbC2[j]);
                const float h0 = fmaxf(f.x, 0.f), h1 = fmaxf(f.y, 0.f);
                pr += h0 * s_wc2[3 * (2 * j) + 0] + h1 * s_wc2[3 * (2 * j + 1) + 0];
                pg += h0 * s_wc2[3 * (2 * j) + 1] + h1 * s_wc2[3 * (2 * j + 1) + 1];
                pb += h0 * s_wc2[3 * (2 * j) + 2] + h1 * s_wc2[3 * (2 * j + 1) + 2];
            }
            R = 1.f / (1.f + __expf(-pr));
            G = 1.f / (1.f + __expf(-pg));
            B = 1.f / (1.f + __expf(-pb));
        }

        float incl = sv;
        #pragma unroll
        for (int off = 1; off < 64; off <<= 1) {
            float t = __shfl_up(incl, off);
            if (lane >= off) incl += t;
        }
        const float e = carry + (incl - sv);
        const float w = valid ? (1.f - __expf(-sv)) * __expf(-e) : 0.f;
        accw += w; cr += w * R; cg += w * G; cb += w * B;
        carry += __shfl(incl, 63);
    }

    #pragma unroll
    for (int off = 32; off > 0; off >>= 1) {
        accw += __shfl_down(accw, off);
        cr   += __shfl_down(cr, off);
        cg   += __shfl_down(cg, off);
        cb   += __shfl_down(cb, off);
    }

    if (lane == 0) {
        const float bgw = 1.f - accw;
        out[0 * HW_NRAYS + r] = clamp01f(cr + bgw);
        out[1 * HW_NRAYS + r] = clamp01f(cg + bgw);
        out[2 * HW_NRAYS + r] = clamp01f(cb + bgw);
        out[3 * HW_NRAYS + r] = clamp01f(accw);
    }
}

// ---------------- fallback (no workspace at all) ----------------
__global__ __launch_bounds__(64, 4)
void ngp_render_ref(const float* __restrict__ rays_o,
                    const float* __restrict__ rays_d,
                    const float* __restrict__ t_starts,
                    const float* __restrict__ t_ends,
                    const int*   __restrict__ ray_idx,
                    const float* __restrict__ tab_d,
                    const float* __restrict__ tab_c,
                    const float* __restrict__ w_d1,
                    const float* __restrict__ w_d2,
                    const float* __restrict__ w_c1,
                    const float* __restrict__ w_c2,
                    float* __restrict__ out)
{
    __shared__ __align__(16) float s_wd1[DIN * HDIM];
    __shared__ __align__(16) float s_wc1[DIN * HDIM];
    __shared__ __align__(16) float s_wd2[HDIM];
    __shared__ __align__(16) float s_wc2[HDIM * 3];

    const int lane = threadIdx.x;
    for (int i = lane; i < DIN * HDIM; i += 64) { s_wd1[i] = w_d1[i]; s_wc1[i] = w_c1[i]; }
    if (lane < HDIM) s_wd2[lane] = w_d2[lane];
    for (int i = lane; i < HDIM * 3; i += 64) s_wc2[i] = w_c2[i];
    __syncthreads();

    const int r = blockIdx.x;
    int lo = 0, hi = NSAMP;
    while (lo < hi) { int m = (lo + hi) >> 1; if (ray_idx[m] < r) lo = m + 1; else hi = m; }
    const int start = lo;
    hi = NSAMP;
    while (lo < hi) { int m = (lo + hi) >> 1; if (ray_idx[m] <= r) lo = m + 1; else hi = m; }
    const int end = lo;

    const float ox = rays_o[3 * r + 0], oy = rays_o[3 * r + 1], oz = rays_o[3 * r + 2];
    const float dx = rays_d[3 * r + 0], dy = rays_d[3 * r + 1], dz = rays_d[3 * r + 2];

    float carry = 0.f, accw = 0.f, cr = 0.f, cg = 0.f, cb = 0.f;

    for (int base = start; base < end; base += 64) {
        const int i = base + lane;
        const bool valid = i < end;
        float sv = 0.f, R = 0.f, G = 0.f, B = 0.f;
        if (valid) {
            const float ts = t_starts[i], te = t_ends[i];
            const float tm = 0.5f * (ts + te);
            const float x01x = clamp01f((ox + dx * tm + 1.f) * 0.5f);
            const float x01y = clamp01f((oy + dy * tm + 1.f) * 0.5f);
            const float x01z = clamp01f((oz + dz * tm + 1.f) * 0.5f);

            float hbD[HDIM], hbC[HDIM];
            #pragma unroll
            for (int j = 0; j < HDIM; ++j) { hbD[j] = 0.f; hbC[j] = 0.f; }

            #pragma unroll 1
            for (int l = 0; l < NLEV; ++l) {
                uint32_t h[8]; float w[8];
                level_hashes(x01x, x01y, x01z, l, h, w);
                const float* td = tab_d + (size_t)l * (TSZ * 2);
                const float* tc = tab_c + (size_t)l * (TSZ * 2);
                float a0 = 0.f, a1 = 0.f, b0 = 0.f, b1 = 0.f;
                #pragma unroll
                for (int c = 0; c < 8; ++c) {
                    const float2 vd = *(const float2*)(td + (size_t)(h[c] * 2u));
                    const float2 vc = *(const float2*)(tc + (size_t)(h[c] * 2u));
                    a0 += w[c] * vd.x; a1 += w[c] * vd.y; b0 += w[c] * vc.x; b1 += w[c] * vc.y;
                }
                #pragma unroll
                for (int j = 0; j < HDIM; j += 4) {
                    const float4 u0 = *(const float4*)(s_wd1 + (2 * l + 0) * HDIM + j);
                    const float4 u1 = *(const float4*)(s_wd1 + (2 * l + 1) * HDIM + j);
                    hbD[j + 0] += a0 * u0.x + a1 * u1.x;
                    hbD[j + 1] += a0 * u0.y + a1 * u1.y;
                    hbD[j + 2] += a0 * u0.z + a1 * u1.z;
                    hbD[j + 3] += a0 * u0.w + a1 * u1.w;
                    const float4 v0 = *(const float4*)(s_wc1 + (2 * l + 0) * HDIM + j);
                    const float4 v1 = *(const float4*)(s_wc1 + (2 * l + 1) * HDIM + j);
                    hbC[j + 0] += b0 * v0.x + b1 * v1.x;
                    hbC[j + 1] += b0 * v0.y + b1 * v1.y;
                    hbC[j + 2] += b0 * v0.z + b1 * v1.z;
                    hbC[j + 3] += b0 * v0.w + b1 * v1.w;
                }
            }

            float dotv = 0.f;
            #pragma unroll
            for (int j = 0; j < HDIM; ++j) dotv += fmaxf(hbD[j], 0.f) * s_wd2[j];
            sv = __expf(dotv) * (te - ts);

            float pr = 0.f, pg = 0.f, pb = 0.f;
            #pragma unroll
            for (int j = 0; j < HDIM; ++j) {
                const float hj = fmaxf(hbC[j], 0.f);
                pr += hj * s_wc2[3 * j + 0];
                pg += hj * s_wc2[3 * j + 1];
                pb += hj * s_wc2[3 * j + 2];
            }
            R = 1.f / (1.f + __expf(-pr));
            G = 1.f / (1.f + __expf(-pg));
            B = 1.f / (1.f + __expf(-pb));
        }

        float incl = sv;
        #pragma unroll
        for (int off = 1; off < 64; off <<= 1) {
            float t = __shfl_up(incl, off);
            if (lane >= off) incl += t;
        }
        const float e = carry + (incl - sv);
        const float w = valid ? (1.f - __expf(-sv)) * __expf(-e) : 0.f;
        accw += w; cr += w * R; cg += w * G; cb += w * B;
        carry += __shfl(incl, 63);
    }

    #pragma unroll
    for (int off = 32; off > 0; off >>= 1) {
        accw += __shfl_down(accw, off);
        cr   += __shfl_down(cr, off);
        cg   += __shfl_down(cg, off);
        cb   += __shfl_down(cb, off);
    }

    if (lane == 0) {
        const float bgw = 1.f - accw;
        out[0 * HW_NRAYS + r] = clamp01f(cr + bgw);
        out[1 * HW_NRAYS + r] = clamp01f(cg + bgw);
        out[2 * HW_NRAYS + r] = clamp01f(cb + bgw);
        out[3 * HW_NRAYS + r] = clamp01f(accw);
    }
}

extern "C" void kernel_launch(void* const* d_in, const int* in_sizes, int n_in,
                              void* d_out, int out_size, void* d_ws, size_t ws_size,
                              hipStream_t stream) {
    const float* rays_o        = (const float*)d_in[0];
    const float* rays_d        = (const float*)d_in[1];
    const float* t_starts      = (const float*)d_in[2];
    const float* t_ends        = (const float*)d_in[3];
    const int*   ray_indices   = (const int*)d_in[4];
    const float* table_density = (const float*)d_in[5];
    const float* table_color   = (const float*)d_in[6];
    const float* w_d1          = (const float*)d_in[7];
    const float* w_d2          = (const float*)d_in[8];
    const float* w_c1          = (const float*)d_in[9];
    const float* w_c2          = (const float*)d_in[10];
    float* outp = (float*)d_out;

    if (ws_size >= WS_TAB_BYTES + WS_FEAT_BYTES) {
        uint2* ws_tab = (uint2*)d_ws;
        uint2* ws_feat = (uint2*)((char*)d_ws + WS_TAB_BYTES);
        hipLaunchKernelGGL(ngp_pack_tables, dim3(4096), dim3(256), 0, stream,
                           (const float2*)table_density, (const float2*)table_color, ws_tab);
        hipLaunchKernelGGL(ngp_encode, dim3(NLEV * (NSAMP / 256)), dim3(256), 0, stream,
                           rays_o, rays_d, t_starts, t_ends, ray_indices, ws_tab, ws_feat);
        hipLaunchKernelGGL(ngp_render_feat, dim3(HW_NRAYS / 4), dim3(256), 0, stream,
                           t_starts, t_ends, ray_indices, ws_feat,
                           w_d1, w_d2, w_c1, w_c2, outp);
    } else if (ws_size >= WS_TAB_BYTES) {
        uint2* ws_tab = (uint2*)d_ws;
        hipLaunchKernelGGL(ngp_pack_tables, dim3(4096), dim3(256), 0, stream,
                           (const float2*)table_density, (const float2*)table_color, ws_tab);
        hipLaunchKernelGGL(ngp_render_fast, dim3(HW_NRAYS / 4), dim3(256), 0, stream,
                           rays_o, rays_d, t_starts, t_ends, ray_indices, ws_tab,
                           w_d1, w_d2, w_c1, w_c2, outp);
    } else {
        hipLaunchKernelGGL(ngp_render_ref, dim3(HW_NRAYS), dim3(64), 0, stream,
                           rays_o, rays_d, t_starts, t_ends, ray_indices,
                           table_density, table_color,
                           w_d1, w_d2, w_c1, w_c2, outp);
    }
}